// Round 9
// baseline (631.727 us; speedup 1.0000x reference)
//
#include <hip/hip_runtime.h>
#include <hip/hip_bf16.h>
#include <math.h>

#define BB 4
#define SS 4096
#define DDIM 1024
#define KSEL 8
#define NR 16
#define NC 16
#define MID 256
#define RC 256
#define TOK (BB*SS)

typedef __hip_bfloat16 bf16;
typedef short short8 __attribute__((ext_vector_type(8)));
typedef short short4v __attribute__((ext_vector_type(4)));
typedef float floatx4 __attribute__((ext_vector_type(4)));
typedef float floatx16 __attribute__((ext_vector_type(16)));
#define MFMA16(a,b,c) __builtin_amdgcn_mfma_f32_16x16x32_bf16(a,b,c,0,0,0)
#define MFMA32(a,b,c) __builtin_amdgcn_mfma_f32_32x32x16_bf16(a,b,c,0,0,0)

__device__ __forceinline__ float uihf(unsigned v) { union { unsigned i; float f; } t; t.i = v; return t.f; }
__device__ __forceinline__ float b2f(bf16 h) { return __bfloat162float(h); }
__device__ __forceinline__ float bs2f(short s) { return uihf(((unsigned)(unsigned short)s) << 16); }
__device__ __forceinline__ short f2bs(float f) {
    bf16 h = __float2bfloat16(f);
    return *reinterpret_cast<short*>(&h);
}
__device__ __forceinline__ float loadf(const void* p, size_t i, bool f32m) {
    return f32m ? ((const float*)p)[i] : b2f(((const bf16*)p)[i]);
}

// ws layout (float offsets)
#define WS_RB   16
#define WS_CB2  4112
#define WS_CB1  8208
#define WS_CW   24592
#define WS_BIAS 286736
#define WS_QK   287760                     // short area: Q [TOK][256] then KK [TOK][256]
#define WS_WB   4482064                    // short area: W bf16 [1024][1024]
#define WS_XT   5006352                    // short area: xT bf16 [BB][DDIM][SS]
#define WS_LV   13394960                   // [TOK] f32 (legacy, unused by fused path)

struct DetectArgs { const void* p[9]; int n[9]; };

// --------- dtype detector (+ block 9: zero WS_RB..WS_CB1 for atomics) --------
__global__ void k_detect(DetectArgs A, int* __restrict__ flags) {
    int b = blockIdx.x;
    int tid = threadIdx.x;
    if (b == 9) {   // zero RB (4K) + CB2 (4K, plain-store later, harmless) + CB1 (16K)
        float* w = (float*)flags;
        for (int i = tid; i < 24576; i += 256) w[WS_RB + i] = 0.f;
        return;
    }
    const unsigned short* u = (const unsigned short*)A.p[b];
    int n = A.n[b]; if (n > 4096) n = 4096;
    float m = 0.f;
    for (int i = tid; i < n; i += 256) {
        unsigned v = (((unsigned)u[i]) << 16) & 0x7fffffffu;
        float f = uihf(v);
        if (f == f) m = fmaxf(m, f);
    }
    for (int o = 32; o; o >>= 1) m = fmaxf(m, __shfl_xor(m, o));
    __shared__ float red[4];
    if ((tid & 63) == 0) red[tid >> 6] = m;
    __syncthreads();
    if (tid == 0) {
        float mm = fmaxf(fmaxf(red[0], red[1]), fmaxf(red[2], red[3]));
        flags[b] = (b == 1) ? 0 : (mm > 1e4f ? 1 : 0);
    }
}

// ---------------- basis sums ----------------
// 128 blocks: row r = bx>>3, d-chunk = bx&7 (128 d each); atomicAdd partials.
__global__ void k_rbsum(const void* __restrict__ rb, float* __restrict__ ws) {
    bool f32m = ((const int*)ws)[4] != 0;
    int r = blockIdx.x >> 3, dc = blockIdx.x & 7, m = threadIdx.x;
    size_t base = (size_t)r*DDIM*MID + (size_t)dc*128*MID + m;
    float s = 0.f;
    #pragma unroll 8
    for (int d = 0; d < 128; ++d) s += loadf(rb, base + (size_t)d*MID, f32m);
    atomicAdd(&ws[WS_RB + r*MID + m], s);
}

__global__ void k_cb2(const void* __restrict__ cb, float* __restrict__ ws) {
    bool f32m = ((const int*)ws)[5] != 0;
    int row = blockIdx.x*4 + (threadIdx.x >> 6);
    int lane = threadIdx.x & 63;
    size_t base = (size_t)row*DDIM;
    float s = 0.f;
    for (int i = lane; i < DDIM; i += 64) s += loadf(cb, base + i, f32m);
    for (int o = 32; o; o >>= 1) s += __shfl_down(s, o);
    if (lane == 0) ws[WS_CB2 + row] = s;
}

// 256 blocks: c = bx>>4, d-chunk = (bx>>2)&3, m-chunk = bx&3; atomicAdd.
__global__ void k_cb1(const void* __restrict__ cb, float* __restrict__ ws) {
    bool f32m = ((const int*)ws)[5] != 0;
    int c = blockIdx.x >> 4;
    int d = (((blockIdx.x >> 2) & 3) << 8) + threadIdx.x;
    int m0 = (blockIdx.x & 3) * 64;
    size_t base = (size_t)c*MID*DDIM + (size_t)m0*DDIM + d;
    float s = 0.f;
    #pragma unroll 8
    for (int m = 0; m < 64; ++m) s += loadf(cb, base + (size_t)m*DDIM, f32m);
    atomicAdd(&ws[WS_CB1 + c*DDIM + d], s);
}

// ---------------- W -> bf16, bias -> f32 ----------------
__global__ void k_wcvt(const void* __restrict__ w, const void* __restrict__ bias,
                       float* __restrict__ ws) {
    bool wf32 = ((const int*)ws)[6] != 0, bf32 = ((const int*)ws)[7] != 0;
    short* Wb = (short*)(ws + WS_WB);
    float* biasf = ws + WS_BIAS;
    int bx = blockIdx.x, tid = threadIdx.x;
    if (bx == 512) {
        for (int i = tid; i < DDIM; i += 256) biasf[i] = loadf(bias, i, bf32);
        return;
    }
    size_t base = (size_t)bx*2048 + tid*8;
    if (wf32) {
        const float* s = (const float*)w + base;
        float4 a = *(const float4*)s, c = *(const float4*)(s + 4);
        short8 v;
        v[0]=f2bs(a.x); v[1]=f2bs(a.y); v[2]=f2bs(a.z); v[3]=f2bs(a.w);
        v[4]=f2bs(c.x); v[5]=f2bs(c.y); v[6]=f2bs(c.z); v[7]=f2bs(c.w);
        *(short8*)(Wb + base) = v;
    } else {
        *(uint4*)(Wb + base) = *(const uint4*)((const short*)w + base);
    }
}

// ---------------- x [b][s][d] -> xT bf16 [b][d][s] ----------------
__global__ void k_xt(const void* __restrict__ x, float* __restrict__ ws) {
    bool xf32 = ((const int*)ws)[0] != 0;
    __shared__ short T[64][72];
    int tid = threadIdx.x;
    int s0 = blockIdx.x*64, d0 = blockIdx.y*64, b = blockIdx.z;
    int rr = tid >> 4, c4 = (tid & 15)*4;
    #pragma unroll
    for (int it = 0; it < 4; ++it) {
        int r = rr + it*16;
        size_t off = (size_t)(b*SS + s0 + r)*DDIM + d0 + c4;
        float v[4];
        if (xf32) {
            float4 a = *(const float4*)((const float*)x + off);
            v[0]=a.x; v[1]=a.y; v[2]=a.z; v[3]=a.w;
        } else {
            const short* p = (const short*)x + off;
            #pragma unroll
            for (int j = 0; j < 4; ++j) v[j] = bs2f(p[j]);
        }
        #pragma unroll
        for (int j = 0; j < 4; ++j) T[c4+j][r] = f2bs(v[j]);
    }
    __syncthreads();
    int dr = tid >> 2, sc = (tid & 3)*16;
    short8 u0 = *(const short8*)(&T[dr][sc]);
    short8 u1 = *(const short8*)(&T[dr][sc+8]);
    short* dst = (short*)(ws + WS_XT) + ((size_t)(b*DDIM + d0 + dr))*SS + s0 + sc;
    *(short8*)dst = u0;
    *(short8*)(dst + 8) = u1;
}

// ---------------- routing: per-token q, kk, col_w (one WAVE per token) -------
__global__ __launch_bounds__(256) void k_route(const int* __restrict__ nidx,
        const void* __restrict__ nw, const void* __restrict__ rmat,
        float* __restrict__ ws) {
    const bool f2 = ((const int*)ws)[2] != 0, f3 = ((const int*)ws)[3] != 0;
    const int lane = threadIdx.x & 63;
    const int tok = blockIdx.x*4 + (threadIdx.x >> 6);

    int idx8 = 0; float w8 = 0.f;
    if (lane < KSEL) {
        idx8 = nidx[tok*KSEL + lane];
        w8   = loadf(nw, tok*KSEL + lane, f2);
    }

    float acc[4] = {0.f,0.f,0.f,0.f};
    #pragma unroll 1
    for (int k = 0; k < KSEL; ++k) {
        int   id_k = __shfl(idx8, k);
        float wk   = __shfl(w8, k);
        float v[4];
        if (f3) {
            float4 t = *(const float4*)((const float*)rmat + (size_t)id_k*RC + lane*4);
            v[0]=t.x; v[1]=t.y; v[2]=t.z; v[3]=t.w;
        } else {
            short4v t = *(const short4v*)((const short*)rmat + (size_t)id_k*RC + lane*4);
            #pragma unroll
            for (int j = 0; j < 4; ++j) v[j] = bs2f(t[j]);
        }
        float m = fmaxf(fmaxf(v[0],v[1]), fmaxf(v[2],v[3]));
        #pragma unroll
        for (int o = 32; o; o >>= 1) m = fmaxf(m, __shfl_xor(m, o));
        float e[4], s = 0.f;
        #pragma unroll
        for (int j = 0; j < 4; ++j) { e[j] = __expf(v[j]-m); s += e[j]; }
        #pragma unroll
        for (int o = 32; o; o >>= 1) s += __shfl_xor(s, o);
        float r = wk / s;
        #pragma unroll
        for (int j = 0; j < 4; ++j) acc[j] += r * e[j];
    }
    {   // final softmax over the 256-element token recipe
        float m = fmaxf(fmaxf(acc[0],acc[1]), fmaxf(acc[2],acc[3]));
        #pragma unroll
        for (int o = 32; o; o >>= 1) m = fmaxf(m, __shfl_xor(m, o));
        float s = 0.f;
        #pragma unroll
        for (int j = 0; j < 4; ++j) { acc[j] = __expf(acc[j]-m); s += acc[j]; }
        #pragma unroll
        for (int o = 32; o; o >>= 1) s += __shfl_xor(s, o);
        float inv = 1.f / s;
        #pragma unroll
        for (int j = 0; j < 4; ++j) acc[j] *= inv;
    }
    float rwp = acc[0]+acc[1]+acc[2]+acc[3];
    rwp += __shfl_xor(rwp, 1); rwp += __shfl_xor(rwp, 2);
    float cw4[4] = {acc[0],acc[1],acc[2],acc[3]};
    #pragma unroll
    for (int j = 0; j < 4; ++j) {
        cw4[j] += __shfl_xor(cw4[j], 4);
        cw4[j] += __shfl_xor(cw4[j], 8);
        cw4[j] += __shfl_xor(cw4[j], 16);
        cw4[j] += __shfl_xor(cw4[j], 32);
    }
    if (lane < 4) {
        float4 t; t.x=cw4[0]; t.y=cw4[1]; t.z=cw4[2]; t.w=cw4[3];
        *(float4*)(ws + WS_CW + (size_t)tok*NC + lane*4) = t;
    }
    float rwAll[NR], cwAll[NC];
    #pragma unroll
    for (int r = 0; r < NR; ++r) rwAll[r] = __shfl(rwp, r*4);
    #pragma unroll
    for (int c = 0; c < NC; ++c) cwAll[c] = __shfl(cw4[c & 3], c >> 2);
    float qv[4] = {0.f,0.f,0.f,0.f}, kv[4] = {0.f,0.f,0.f,0.f};
    #pragma unroll
    for (int r = 0; r < NR; ++r) {
        float4 t = *(const float4*)(ws + WS_RB + r*MID + lane*4);
        qv[0] += rwAll[r]*t.x; qv[1] += rwAll[r]*t.y;
        qv[2] += rwAll[r]*t.z; qv[3] += rwAll[r]*t.w;
    }
    #pragma unroll
    for (int c = 0; c < NC; ++c) {
        float4 t = *(const float4*)(ws + WS_CB2 + c*MID + lane*4);
        kv[0] += cwAll[c]*t.x; kv[1] += cwAll[c]*t.y;
        kv[2] += cwAll[c]*t.z; kv[3] += cwAll[c]*t.w;
    }
    short* Qh  = (short*)(ws + WS_QK);
    short* KKh = Qh + (size_t)TOK*MID;
    short4v qo, ko;
    #pragma unroll
    for (int j = 0; j < 4; ++j) { qo[j] = f2bs(qv[j]*0.0625f); ko[j] = f2bs(kv[j]); }
    *(short4v*)(Qh  + (size_t)tok*MID + lane*4) = qo;
    *(short4v*)(KKh + (size_t)tok*MID + lane*4) = ko;
}

// ---- k_att v4: producer/consumer fused attention, 512 threads, d=512 -------
// Waves 0-3 PRODUCERS: stage Ks (reg-prefetched), QK^T MFMA, exp, write
// Ps[parity]. Waves 4-7 CONSUMERS: PV MFMA from Ps[parity^1] (one iter
// behind), xf global loads, epilogue. QK(it) and PV(it-1) run CONCURRENTLY
// in phase B -> iteration cost ~ max(QK, PV) instead of sum, and 2 waves/SIMD
// hide LDS/MFMA latency (R7 had 1 wave/SIMD, everything latency-serial).
// Balance: block owns qt-pair {63-qtp, qtp} = exactly 130 iters. Grid 256.
// Phase/barrier schedule per half-iteration:
//   A: producers Ks<-kp, kp<-K(next)        | consumers idle
//   BAR   (Ks ready; Ps[p^1] from prev B complete)
//   B: producers QK(it)->Ps[p]              | consumers PV(it-1) from Ps[p^1],
//                                           |   then load xfS=xf(it)
//   BAR   (Ps[p] done; Ks consumed)
// ntiles is always even -> manual 2x unroll gives static Ps parity (rule #20).
__global__ __launch_bounds__(512) void k_att(const float* __restrict__ ws,
        float* __restrict__ U, const void* __restrict__ alphap) {
    __shared__ __align__(16) short Ks[32*264];     // 16.9 KB
    __shared__ __align__(16) short Ps[2*64*40];    // 10.2 KB
    __shared__ __align__(16) short cb1T[512*40];   // 41.0 KB
    __shared__ __align__(16) short cwsb[64*40];    //  5.1 KB
    __shared__ float lv[64];
    const int tid = threadIdx.x;
    const int w = tid >> 6, lane = tid & 63, lq = lane & 15, quad = lane >> 4;
    const bool prod = (w < 4);
    const int wp = w & 3;                          // role-local wave id
    const int d0 = blockIdx.x*512, b = blockIdx.y, qtp = blockIdx.z;
    const bool af32 = ((const int*)ws)[8] != 0;
    const short* Qh  = (const short*)(ws + WS_QK);
    const short* KKh = Qh + (size_t)TOK*MID;
    const short* xT  = (const short*)(ws + WS_XT);

    {   // stage cb1T [512 d][16 c] once: one row per thread
        const float* src = ws + WS_CB1 + d0 + tid;
        short* dst = cb1T + tid*40;
        #pragma unroll
        for (int c = 0; c < 16; ++c) dst[c] = f2bs(src[c*DDIM]);
        #pragma unroll
        for (int c = 16; c < 32; ++c) dst[c] = 0;
    }

    // Ps swizzle bases (as R6/R7): producer write base, consumer read base
    const int rsw = (lq >> 2) & 3;
    const short* pa_rd = Ps + lq*40 + ((quad ^ rsw) << 3);       // consumer
    short* pd_base = Ps + (wp*16 + quad*4)*40 + (lq & 7);        // producer
    // K staging geometry (producers = tid 0..255): row kr, cols ksg..+32
    const int kr = tid >> 3, ksg = (tid & 7)*32;
    short* kdst = Ks + kr*264 + ksg;
    const short* ksrc0 = KKh + (size_t)(b*SS + kr)*MID + ksg;
    // consumer xf base (c = wp for waves 4-7)
    const short* xb_base = xT + (size_t)(b*DDIM + d0 + wp*128 + lq)*SS + quad*8;
    float alpha = af32 ? ((const float*)alphap)[0] : bs2f(((const short*)alphap)[0]);

    short8 qa[8];                 // producer: Q fragment (16 q-rows)
    short8 kp0, kp1, kp2, kp3;    // producer: K prefetch regs
    floatx4 acc[4][8];            // consumer: [qi][di]
    short8 xs0, xs1, xs2, xs3, xs4, xs5, xs6, xs7;   // consumer xf
    float l[4];

#define KSTAGE() do { \
    *(short8*)(kdst)      = kp0; \
    *(short8*)(kdst + 8)  = kp1; \
    *(short8*)(kdst + 16) = kp2; \
    *(short8*)(kdst + 24) = kp3; \
} while (0)
#define KPREF(IT) do { \
    const short* kn_ = ksrc0 + (size_t)(IT)*32*MID; \
    kp0 = *(const short8*)(kn_); \
    kp1 = *(const short8*)(kn_ + 8); \
    kp2 = *(const short8*)(kn_ + 16); \
    kp3 = *(const short8*)(kn_ + 24); \
} while (0)
#define QK(IT, PSOFF) do { \
    const int t0_ = (IT)*32; \
    _Pragma("unroll") \
    for (int h = 0; h < 2; ++h) { \
        floatx4 s_ = (floatx4){0.f,0.f,0.f,0.f}; \
        const short* kb_ = Ks + (h*16 + lq)*264 + quad*8; \
        _Pragma("unroll") \
        for (int ks = 0; ks < 8; ++ks) \
            s_ = MFMA16(qa[ks], *(const short8*)(kb_ + ks*32), s_); \
        int t_ = t0_ + h*16 + lq; \
        short* pd_ = pd_base + (PSOFF) + (((h*2 + (lq >> 3)) ^ quad) << 3); \
        _Pragma("unroll") \
        for (int r = 0; r < 4; ++r) { \
            float p_ = (t_ <= qg + r) ? __expf(s_[r]) : 0.f; \
            l[r] += p_; \
            pd_[r*40] = f2bs(p_); \
        } \
    } \
} while (0)
#define PVS(PSOFF) do { \
    const short* pr_ = pa_rd + (PSOFF); \
    short8 pa0 = *(const short8*)(pr_); \
    short8 pa1 = *(const short8*)(pr_ + 640); \
    short8 pa2 = *(const short8*)(pr_ + 1280); \
    short8 pa3 = *(const short8*)(pr_ + 1920); \
    acc[0][0] = MFMA16(pa0, xs0, acc[0][0]); \
    acc[1][0] = MFMA16(pa1, xs0, acc[1][0]); \
    acc[2][0] = MFMA16(pa2, xs0, acc[2][0]); \
    acc[3][0] = MFMA16(pa3, xs0, acc[3][0]); \
    acc[0][1] = MFMA16(pa0, xs1, acc[0][1]); \
    acc[1][1] = MFMA16(pa1, xs1, acc[1][1]); \
    acc[2][1] = MFMA16(pa2, xs1, acc[2][1]); \
    acc[3][1] = MFMA16(pa3, xs1, acc[3][1]); \
    acc[0][2] = MFMA16(pa0, xs2, acc[0][2]); \
    acc[1][2] = MFMA16(pa1, xs2, acc[1][2]); \
    acc[2][2] = MFMA16(pa2, xs2, acc[2][2]); \
    acc[3][2] = MFMA16(pa3, xs2, acc[3][2]); \
    acc[0][3] = MFMA16(pa0, xs3, acc[0][3]); \
    acc[1][3] = MFMA16(pa1, xs3, acc[1][3]); \
    acc[2][3] = MFMA16(pa2, xs3, acc[2][3]); \
    acc[3][3] = MFMA16(pa3, xs3, acc[3][3]); \
    acc[0][4] = MFMA16(pa0, xs4, acc[0][4]); \
    acc[1][4] = MFMA16(pa1, xs4, acc[1][4]); \
    acc[2][4] = MFMA16(pa2, xs4, acc[2][4]); \
    acc[3][4] = MFMA16(pa3, xs4, acc[3][4]); \
    acc[0][5] = MFMA16(pa0, xs5, acc[0][5]); \
    acc[1][5] = MFMA16(pa1, xs5, acc[1][5]); \
    acc[2][5] = MFMA16(pa2, xs5, acc[2][5]); \
    acc[3][5] = MFMA16(pa3, xs5, acc[3][5]); \
    acc[0][6] = MFMA16(pa0, xs6, acc[0][6]); \
    acc[1][6] = MFMA16(pa1, xs6, acc[1][6]); \
    acc[2][6] = MFMA16(pa2, xs6, acc[2][6]); \
    acc[3][6] = MFMA16(pa3, xs6, acc[3][6]); \
    acc[0][7] = MFMA16(pa0, xs7, acc[0][7]); \
    acc[1][7] = MFMA16(pa1, xs7, acc[1][7]); \
    acc[2][7] = MFMA16(pa2, xs7, acc[2][7]); \
    acc[3][7] = MFMA16(pa3, xs7, acc[3][7]); \
} while (0)
#define XLOAD(IT) do { \
    const short* xx_ = xb_base + (IT)*32; \
    xs0 = *(const short8*)(xx_); \
    xs1 = *(const short8*)(xx_ + (size_t)16*SS); \
    xs2 = *(const short8*)(xx_ + (size_t)32*SS); \
    xs3 = *(const short8*)(xx_ + (size_t)48*SS); \
    xs4 = *(const short8*)(xx_ + (size_t)64*SS); \
    xs5 = *(const short8*)(xx_ + (size_t)80*SS); \
    xs6 = *(const short8*)(xx_ + (size_t)96*SS); \
    xs7 = *(const short8*)(xx_ + (size_t)112*SS); \
} while (0)

    #pragma unroll 1
    for (int ph = 0; ph < 2; ++ph) {
        const int qt = ph ? qtp : 63 - qtp;
        const int q0 = qt*64;
        const int ntiles = 2*qt + 2;                 // even, >= 2
        const int qg = q0 + wp*16 + quad*4;          // producer mask row base
        __syncthreads();   // all prev-ph LDS readers done
        if (tid < 256) {   // stage cw rows for this q0 (producers' threads)
            int r = tid >> 2, c4 = (tid & 3)*4;
            const float* cwp = ws + WS_CW + (size_t)(b*SS + q0 + r)*NC + c4;
            short* dst = cwsb + r*40;
            #pragma unroll
            for (int j = 0; j < 4; ++j) dst[c4 + j] = f2bs(cwp[j]);
            #pragma unroll
            for (int j = 0; j < 4; ++j) dst[16 + c4 + j] = 0;
        }
        if (prod) {
            const short* qrow = Qh + (size_t)(b*SS + q0 + wp*16 + lq)*MID + quad*8;
            #pragma unroll
            for (int ks = 0; ks < 8; ++ks) qa[ks] = *(const short8*)(qrow + ks*32);
            KPREF(0);
            l[0] = l[1] = l[2] = l[3] = 0.f;
        } else {
            #pragma unroll
            for (int qi = 0; qi < 4; ++qi)
                #pragma unroll
                for (int di = 0; di < 8; ++di) acc[qi][di] = (floatx4){0.f,0.f,0.f,0.f};
        }

        #pragma unroll 1
        for (int it = 0; it < ntiles; it += 2) {
            // ---------- even half (Ps parity 0) ----------
            if (prod) { KSTAGE(); KPREF(it + 1); }
            __syncthreads();                 // Ks(it) ready; Ps1 (prev) complete
            if (prod) {
                QK(it, 0);
            } else {
                if (it > 0) PVS(2560);       // PV(it-1) from Ps1, xfS=xf(it-1)
                XLOAD(it);                   // xfS = xf(it)
            }
            __syncthreads();                 // Ps0 done; Ks consumed
            // ---------- odd half (Ps parity 1) ----------
            if (prod) { KSTAGE(); if (it + 2 < ntiles) KPREF(it + 2); }
            __syncthreads();                 // Ks(it+1) ready; Ps0 complete
            if (prod) {
                QK(it + 1, 2560);
            } else {
                PVS(0);                      // PV(it) from Ps0, xfS=xf(it)
                XLOAD(it + 1);               // xfS = xf(it+1)
            }
            __syncthreads();                 // Ps1 done; Ks consumed
        }
        // tail: PV(ntiles-1) from Ps1; producers publish l
        if (prod) {
            #pragma unroll
            for (int r = 0; r < 4; ++r) {
                float v = l[r];
                v += __shfl_xor(v,1); v += __shfl_xor(v,2);
                v += __shfl_xor(v,4); v += __shfl_xor(v,8);
                if (lq == 0) lv[wp*16 + quad*4 + r] = v;
            }
        } else {
            PVS(2560);
        }
        __syncthreads();                     // lv ready
        if (!prod) {   // epilogue: consumers write U for their d-slice
            float linv[4][4];
            #pragma unroll
            for (int qi = 0; qi < 4; ++qi)
                #pragma unroll
                for (int r = 0; r < 4; ++r)
                    linv[qi][r] = 1.f / lv[qi*16 + quad*4 + r];
            short8 ca[4];
            #pragma unroll
            for (int qi = 0; qi < 4; ++qi)
                ca[qi] = *(const short8*)(cwsb + (qi*16 + lq)*40 + quad*8);
            #pragma unroll
            for (int di = 0; di < 8; ++di) {
                const int dl = wp*128 + di*16;
                const short8 cbf = *(const short8*)(cb1T + (dl + lq)*40 + quad*8);
                #pragma unroll
                for (int qi = 0; qi < 4; ++qi) {
                    floatx4 tr = (floatx4){0.f,0.f,0.f,0.f};
                    tr = MFMA16(ca[qi], cbf, tr);
                    float* Ub = U + (size_t)(b*SS + q0 + qi*16 + quad*4)*DDIM + d0 + dl + lq;
                    #pragma unroll
                    for (int r = 0; r < 4; ++r) {
                        float u = acc[qi][di][r]*linv[qi][r] + alpha*tr[r];
                        float e2 = __expf(1.5957691216f*(u + 0.044715f*u*u*u));
                        float th = 1.f - 2.f/(e2 + 1.f);
                        Ub[(size_t)r*DDIM] = 0.5f*u*(1.f + th);
                    }
                }
            }
        }
    }
#undef KSTAGE
#undef KPREF
#undef QK
#undef PVS
#undef XLOAD
}

// --------- final MFMA GEMM v2, in-place on d_out: out = U @ W^T + bias -------
__global__ __launch_bounds__(256,2) void k_gemm3(float* __restrict__ out,
        const float* __restrict__ ws) {
    __shared__ __align__(16) short Al[32*132];   // 8.4 KB (pad 4 shorts/row)
    const int tid = threadIdx.x;
    const int w = tid >> 6, lane = tid & 63;
    const int col = lane & 31, kh = lane >> 5;   // MFMA32: row/col = lane&31, k-half = lane>>5
    const int m0 = blockIdx.x*32;
    const int n0 = w*256;
    const short* Wb = (const short*)(ws + WS_WB);
    const float* biasf = ws + WS_BIAS;

    floatx16 acc[8];
    #pragma unroll
    for (int nt = 0; nt < 8; ++nt)
        #pragma unroll
        for (int r = 0; r < 16; ++r) acc[nt][r] = 0.f;

    const int srow = tid >> 3, sk = (tid & 7)*16;
    const float* Usrc = out + (size_t)(m0 + srow)*DDIM + sk;
    short* Adst = Al + srow*132 + sk;

    #pragma unroll 1
    for (int kc = 0; kc < DDIM; kc += 128) {
        __syncthreads();
        {   // stage A chunk [32][128] f32 -> bf16
            const float* s = Usrc + kc;
            float4 a = *(const float4*)s,     b4 = *(const float4*)(s + 4);
            float4 c = *(const float4*)(s+8), d  = *(const float4*)(s + 12);
            short8 v0, v1;
            v0[0]=f2bs(a.x);  v0[1]=f2bs(a.y);  v0[2]=f2bs(a.z);  v0[3]=f2bs(a.w);
            v0[4]=f2bs(b4.x); v0[5]=f2bs(b4.y); v0[6]=f2bs(b4.z); v0[7]=f2bs(b4.w);
            v1[0]=f2bs(c.x);  v1[1]=f2bs(c.y);  v1[2]=f2bs(c.z);  v1[3]=f2bs(c.w);
            v1[4]=f2bs(d.x);  v1[5]=f2bs(d.y);  v1[6]=f2bs(d.z);  v1[7]=f2bs(d.w);
            *(short8*)(Adst)     = v0;
            *(short8*)(Adst + 8) = v1;
        }
        __syncthreads();
        const short* wbp0 = Wb + (size_t)(n0 + col)*DDIM + kc + kh*8;
        #pragma unroll
        for (int ks = 0; ks < 8; ++ks) {
            short8 af = *(const short8*)(Al + col*132 + ks*16 + kh*8);
            const short* wbp = wbp0 + ks*16;
            #pragma unroll
            for (int nt = 0; nt < 8; ++nt)
                acc[nt] = MFMA32(af, *(const short8*)(wbp + (size_t)nt*32*DDIM), acc[nt]);
        }
    }
    // all U reads finished at the last staging barrier -> in-place write safe
    #pragma unroll
    for (int nt = 0; nt < 8; ++nt) {
        int c = n0 + nt*32 + col;
        float bb = biasf[c];
        #pragma unroll
        for (int r = 0; r < 16; ++r) {
            int row = (r & 3) + 8*(r >> 2) + 4*kh;
            out[(size_t)(m0 + row)*DDIM + c] = acc[nt][r] + bb;
        }
    }
}

extern "C" void kernel_launch(void* const* d_in, const int* in_sizes, int n_in,
                              void* d_out, int out_size, void* d_ws, size_t ws_size,
                              hipStream_t stream) {
    (void)out_size; (void)ws_size;
    const void* x    = d_in[0];
    const int*  nidx = (const int*)d_in[1];
    const void* nw   = d_in[2];
    const void* rmat = d_in[3];
    const void* rb   = d_in[4];
    const void* cb   = d_in[5];
    const void* w    = d_in[6];
    const void* bias = d_in[7];
    const void* alpha= d_in[8];
    float* ws = (float*)d_ws;
    float* out = (float*)d_out;

    DetectArgs da;
    for (int i = 0; i < 9; ++i) { da.p[i] = d_in[i]; da.n[i] = (i < n_in) ? in_sizes[i] : 1; }

    k_detect<<<10, 256, 0, stream>>>(da, (int*)ws);
    k_rbsum<<<128, 256, 0, stream>>>(rb, ws);
    k_cb2  <<<1024, 256, 0, stream>>>(cb, ws);
    k_cb1  <<<256, 256, 0, stream>>>(cb, ws);
    k_wcvt <<<513, 256, 0, stream>>>(w, bias, ws);
    k_xt   <<<dim3(SS/64, DDIM/64, BB), 256, 0, stream>>>(x, ws);
    k_route<<<TOK/4, 256, 0, stream>>>(nidx, nw, rmat, ws);
    k_att  <<<dim3(2, BB, 32), 512, 0, stream>>>(ws, out, alpha);
    k_gemm3<<<TOK/32, 256, 0, stream>>>(out, ws);
}

// Round 10
// 584.092 us; speedup vs baseline: 1.0816x; 1.0816x over previous
//
#include <hip/hip_runtime.h>
#include <hip/hip_bf16.h>
#include <math.h>

#define BB 4
#define SS 4096
#define DDIM 1024
#define KSEL 8
#define NR 16
#define NC 16
#define MID 256
#define RC 256
#define TOK (BB*SS)

typedef __hip_bfloat16 bf16;
typedef short short8 __attribute__((ext_vector_type(8)));
typedef short short4v __attribute__((ext_vector_type(4)));
typedef float floatx4 __attribute__((ext_vector_type(4)));
typedef float floatx16 __attribute__((ext_vector_type(16)));
#define MFMA16(a,b,c) __builtin_amdgcn_mfma_f32_16x16x32_bf16(a,b,c,0,0,0)
#define MFMA32(a,b,c) __builtin_amdgcn_mfma_f32_32x32x16_bf16(a,b,c,0,0,0)

__device__ __forceinline__ float uihf(unsigned v) { union { unsigned i; float f; } t; t.i = v; return t.f; }
__device__ __forceinline__ float b2f(bf16 h) { return __bfloat162float(h); }
__device__ __forceinline__ float bs2f(short s) { return uihf(((unsigned)(unsigned short)s) << 16); }
__device__ __forceinline__ short f2bs(float f) {
    bf16 h = __float2bfloat16(f);
    return *reinterpret_cast<short*>(&h);
}
__device__ __forceinline__ float loadf(const void* p, size_t i, bool f32m) {
    return f32m ? ((const float*)p)[i] : b2f(((const bf16*)p)[i]);
}

// ws layout (float offsets)
#define WS_RB   16
#define WS_CB2  4112
#define WS_CB1  8208
#define WS_CW   24592
#define WS_BIAS 286736
#define WS_QK   287760                     // short area: Q [TOK][256] then KK [TOK][256]
#define WS_WB   4482064                    // short area: W bf16 [1024][1024]
#define WS_XT   5006352                    // short area: xT bf16 [BB][DDIM][SS]
#define WS_LV   13394960                   // [TOK] f32 (legacy, unused by fused path)

struct DetectArgs { const void* p[9]; int n[9]; };

// --------- dtype detector (+ block 9: zero WS_RB..WS_CB1 for atomics) --------
__global__ void k_detect(DetectArgs A, int* __restrict__ flags) {
    int b = blockIdx.x;
    int tid = threadIdx.x;
    if (b == 9) {   // zero RB (4K) + CB2 (4K, plain-store later, harmless) + CB1 (16K)
        float* w = (float*)flags;
        for (int i = tid; i < 24576; i += 256) w[WS_RB + i] = 0.f;
        return;
    }
    const unsigned short* u = (const unsigned short*)A.p[b];
    int n = A.n[b]; if (n > 4096) n = 4096;
    float m = 0.f;
    for (int i = tid; i < n; i += 256) {
        unsigned v = (((unsigned)u[i]) << 16) & 0x7fffffffu;
        float f = uihf(v);
        if (f == f) m = fmaxf(m, f);
    }
    for (int o = 32; o; o >>= 1) m = fmaxf(m, __shfl_xor(m, o));
    __shared__ float red[4];
    if ((tid & 63) == 0) red[tid >> 6] = m;
    __syncthreads();
    if (tid == 0) {
        float mm = fmaxf(fmaxf(red[0], red[1]), fmaxf(red[2], red[3]));
        flags[b] = (b == 1) ? 0 : (mm > 1e4f ? 1 : 0);
    }
}

// ---------------- basis sums ----------------
// 128 blocks: row r = bx>>3, d-chunk = bx&7 (128 d each); atomicAdd partials.
__global__ void k_rbsum(const void* __restrict__ rb, float* __restrict__ ws) {
    bool f32m = ((const int*)ws)[4] != 0;
    int r = blockIdx.x >> 3, dc = blockIdx.x & 7, m = threadIdx.x;
    size_t base = (size_t)r*DDIM*MID + (size_t)dc*128*MID + m;
    float s = 0.f;
    #pragma unroll 8
    for (int d = 0; d < 128; ++d) s += loadf(rb, base + (size_t)d*MID, f32m);
    atomicAdd(&ws[WS_RB + r*MID + m], s);
}

__global__ void k_cb2(const void* __restrict__ cb, float* __restrict__ ws) {
    bool f32m = ((const int*)ws)[5] != 0;
    int row = blockIdx.x*4 + (threadIdx.x >> 6);
    int lane = threadIdx.x & 63;
    size_t base = (size_t)row*DDIM;
    float s = 0.f;
    for (int i = lane; i < DDIM; i += 64) s += loadf(cb, base + i, f32m);
    for (int o = 32; o; o >>= 1) s += __shfl_down(s, o);
    if (lane == 0) ws[WS_CB2 + row] = s;
}

// 256 blocks: c = bx>>4, d-chunk = (bx>>2)&3, m-chunk = bx&3; atomicAdd.
__global__ void k_cb1(const void* __restrict__ cb, float* __restrict__ ws) {
    bool f32m = ((const int*)ws)[5] != 0;
    int c = blockIdx.x >> 4;
    int d = (((blockIdx.x >> 2) & 3) << 8) + threadIdx.x;
    int m0 = (blockIdx.x & 3) * 64;
    size_t base = (size_t)c*MID*DDIM + (size_t)m0*DDIM + d;
    float s = 0.f;
    #pragma unroll 8
    for (int m = 0; m < 64; ++m) s += loadf(cb, base + (size_t)m*DDIM, f32m);
    atomicAdd(&ws[WS_CB1 + c*DDIM + d], s);
}

// ---------------- W -> bf16, bias -> f32 ----------------
__global__ void k_wcvt(const void* __restrict__ w, const void* __restrict__ bias,
                       float* __restrict__ ws) {
    bool wf32 = ((const int*)ws)[6] != 0, bf32 = ((const int*)ws)[7] != 0;
    short* Wb = (short*)(ws + WS_WB);
    float* biasf = ws + WS_BIAS;
    int bx = blockIdx.x, tid = threadIdx.x;
    if (bx == 512) {
        for (int i = tid; i < DDIM; i += 256) biasf[i] = loadf(bias, i, bf32);
        return;
    }
    size_t base = (size_t)bx*2048 + tid*8;
    if (wf32) {
        const float* s = (const float*)w + base;
        float4 a = *(const float4*)s, c = *(const float4*)(s + 4);
        short8 v;
        v[0]=f2bs(a.x); v[1]=f2bs(a.y); v[2]=f2bs(a.z); v[3]=f2bs(a.w);
        v[4]=f2bs(c.x); v[5]=f2bs(c.y); v[6]=f2bs(c.z); v[7]=f2bs(c.w);
        *(short8*)(Wb + base) = v;
    } else {
        *(uint4*)(Wb + base) = *(const uint4*)((const short*)w + base);
    }
}

// ---------------- x [b][s][d] -> xT bf16 [b][d][s] ----------------
__global__ void k_xt(const void* __restrict__ x, float* __restrict__ ws) {
    bool xf32 = ((const int*)ws)[0] != 0;
    __shared__ short T[64][72];
    int tid = threadIdx.x;
    int s0 = blockIdx.x*64, d0 = blockIdx.y*64, b = blockIdx.z;
    int rr = tid >> 4, c4 = (tid & 15)*4;
    #pragma unroll
    for (int it = 0; it < 4; ++it) {
        int r = rr + it*16;
        size_t off = (size_t)(b*SS + s0 + r)*DDIM + d0 + c4;
        float v[4];
        if (xf32) {
            float4 a = *(const float4*)((const float*)x + off);
            v[0]=a.x; v[1]=a.y; v[2]=a.z; v[3]=a.w;
        } else {
            const short* p = (const short*)x + off;
            #pragma unroll
            for (int j = 0; j < 4; ++j) v[j] = bs2f(p[j]);
        }
        #pragma unroll
        for (int j = 0; j < 4; ++j) T[c4+j][r] = f2bs(v[j]);
    }
    __syncthreads();
    int dr = tid >> 2, sc = (tid & 3)*16;
    short8 u0 = *(const short8*)(&T[dr][sc]);
    short8 u1 = *(const short8*)(&T[dr][sc+8]);
    short* dst = (short*)(ws + WS_XT) + ((size_t)(b*DDIM + d0 + dr))*SS + s0 + sc;
    *(short8*)dst = u0;
    *(short8*)(dst + 8) = u1;
}

// ---------------- routing: per-token q, kk, col_w (one WAVE per token) -------
__global__ __launch_bounds__(256) void k_route(const int* __restrict__ nidx,
        const void* __restrict__ nw, const void* __restrict__ rmat,
        float* __restrict__ ws) {
    const bool f2 = ((const int*)ws)[2] != 0, f3 = ((const int*)ws)[3] != 0;
    const int lane = threadIdx.x & 63;
    const int tok = blockIdx.x*4 + (threadIdx.x >> 6);

    int idx8 = 0; float w8 = 0.f;
    if (lane < KSEL) {
        idx8 = nidx[tok*KSEL + lane];
        w8   = loadf(nw, tok*KSEL + lane, f2);
    }

    float acc[4] = {0.f,0.f,0.f,0.f};
    #pragma unroll 1
    for (int k = 0; k < KSEL; ++k) {
        int   id_k = __shfl(idx8, k);
        float wk   = __shfl(w8, k);
        float v[4];
        if (f3) {
            float4 t = *(const float4*)((const float*)rmat + (size_t)id_k*RC + lane*4);
            v[0]=t.x; v[1]=t.y; v[2]=t.z; v[3]=t.w;
        } else {
            short4v t = *(const short4v*)((const short*)rmat + (size_t)id_k*RC + lane*4);
            #pragma unroll
            for (int j = 0; j < 4; ++j) v[j] = bs2f(t[j]);
        }
        float m = fmaxf(fmaxf(v[0],v[1]), fmaxf(v[2],v[3]));
        #pragma unroll
        for (int o = 32; o; o >>= 1) m = fmaxf(m, __shfl_xor(m, o));
        float e[4], s = 0.f;
        #pragma unroll
        for (int j = 0; j < 4; ++j) { e[j] = __expf(v[j]-m); s += e[j]; }
        #pragma unroll
        for (int o = 32; o; o >>= 1) s += __shfl_xor(s, o);
        float r = wk / s;
        #pragma unroll
        for (int j = 0; j < 4; ++j) acc[j] += r * e[j];
    }
    {   // final softmax over the 256-element token recipe
        float m = fmaxf(fmaxf(acc[0],acc[1]), fmaxf(acc[2],acc[3]));
        #pragma unroll
        for (int o = 32; o; o >>= 1) m = fmaxf(m, __shfl_xor(m, o));
        float s = 0.f;
        #pragma unroll
        for (int j = 0; j < 4; ++j) { acc[j] = __expf(acc[j]-m); s += acc[j]; }
        #pragma unroll
        for (int o = 32; o; o >>= 1) s += __shfl_xor(s, o);
        float inv = 1.f / s;
        #pragma unroll
        for (int j = 0; j < 4; ++j) acc[j] *= inv;
    }
    float rwp = acc[0]+acc[1]+acc[2]+acc[3];
    rwp += __shfl_xor(rwp, 1); rwp += __shfl_xor(rwp, 2);
    float cw4[4] = {acc[0],acc[1],acc[2],acc[3]};
    #pragma unroll
    for (int j = 0; j < 4; ++j) {
        cw4[j] += __shfl_xor(cw4[j], 4);
        cw4[j] += __shfl_xor(cw4[j], 8);
        cw4[j] += __shfl_xor(cw4[j], 16);
        cw4[j] += __shfl_xor(cw4[j], 32);
    }
    if (lane < 4) {
        float4 t; t.x=cw4[0]; t.y=cw4[1]; t.z=cw4[2]; t.w=cw4[3];
        *(float4*)(ws + WS_CW + (size_t)tok*NC + lane*4) = t;
    }
    float rwAll[NR], cwAll[NC];
    #pragma unroll
    for (int r = 0; r < NR; ++r) rwAll[r] = __shfl(rwp, r*4);
    #pragma unroll
    for (int c = 0; c < NC; ++c) cwAll[c] = __shfl(cw4[c & 3], c >> 2);
    float qv[4] = {0.f,0.f,0.f,0.f}, kv[4] = {0.f,0.f,0.f,0.f};
    #pragma unroll
    for (int r = 0; r < NR; ++r) {
        float4 t = *(const float4*)(ws + WS_RB + r*MID + lane*4);
        qv[0] += rwAll[r]*t.x; qv[1] += rwAll[r]*t.y;
        qv[2] += rwAll[r]*t.z; qv[3] += rwAll[r]*t.w;
    }
    #pragma unroll
    for (int c = 0; c < NC; ++c) {
        float4 t = *(const float4*)(ws + WS_CB2 + c*MID + lane*4);
        kv[0] += cwAll[c]*t.x; kv[1] += cwAll[c]*t.y;
        kv[2] += cwAll[c]*t.z; kv[3] += cwAll[c]*t.w;
    }
    short* Qh  = (short*)(ws + WS_QK);
    short* KKh = Qh + (size_t)TOK*MID;
    short4v qo, ko;
    #pragma unroll
    for (int j = 0; j < 4; ++j) { qo[j] = f2bs(qv[j]*0.0625f); ko[j] = f2bs(kv[j]); }
    *(short4v*)(Qh  + (size_t)tok*MID + lane*4) = qo;
    *(short4v*)(KKh + (size_t)tok*MID + lane*4) = ko;
}

// -------- k_att v5: fused QK^T+exp -> LDS P -> PV(d=512) + gelu -> U ---------
// R7 body (256 threads, d=512 slice, reg-prefetched K, swizzled Ps, 2
// barriers/iter) with grid topology fixed for TLP: ONE qt per block,
// grid 512 1-D = 2 blocks/CU (2 waves/SIMD) so co-resident blocks hide each
// other's LDS/MFMA/global latency (R7 had 1 wave/SIMD, fully latency-serial;
// R8's 512-thread role split spilled to scratch -- reverted).
// qt = 63 - (bx>>3): big blocks dispatch first (LPT — small ones backfill).
// g = bx&7 -> (d0,b): round-robin XCD g keeps each XCD on one (d0,b) ->
// its 4 MB xT panel is L2-resident (T1, paid in R4).
// Resources: 180 VGPR x 2 waves/SIMD = 360 < 512; LDS 68.6KB x 2 = 137 < 160.
__global__ __launch_bounds__(256) void k_att(const float* __restrict__ ws,
        float* __restrict__ U, const void* __restrict__ alphap) {
    __shared__ __align__(16) short Ks[32*264];    // 16.9 KB
    __shared__ __align__(16) short Ps[64*40];     //  5.1 KB
    __shared__ __align__(16) short cb1T[512*40];  // 41.0 KB
    __shared__ __align__(16) short cwsb[64*40];   //  5.1 KB
    __shared__ float lv[64];
    const int tid = threadIdx.x;
    const int w = tid >> 6, lane = tid & 63, lq = lane & 15, quad = lane >> 4;
    const int bx = blockIdx.x;
    const int g = bx & 7;
    const int d0 = (g & 1)*512, b = g >> 1;
    const int qt = 63 - (bx >> 3);               // big q-tiles first (LPT)
    const int q0 = qt*64;
    const int ntiles = 2*qt + 2;
    const bool af32 = ((const int*)ws)[8] != 0;
    const short* Qh  = (const short*)(ws + WS_QK);
    const short* KKh = Qh + (size_t)TOK*MID;
    const short* xT  = (const short*)(ws + WS_XT);

    {   // stage cb1T [512 d][16 c] once (k 16..31 zeroed)
        for (int r = tid; r < 512; r += 256) {
            const float* src = ws + WS_CB1 + d0 + r;
            short* dst = cb1T + r*40;
            #pragma unroll
            for (int c = 0; c < 16; ++c) dst[c] = f2bs(src[c*DDIM]);
            #pragma unroll
            for (int c = 16; c < 32; ++c) dst[c] = 0;
        }
    }
    {   // stage cw rows (k 0..15 = cw, 16..31 = 0)
        int r = tid >> 2, c4 = (tid & 3)*4;
        const float* cwp = ws + WS_CW + (size_t)(b*SS + q0 + r)*NC + c4;
        short* dst = cwsb + r*40;
        #pragma unroll
        for (int j = 0; j < 4; ++j) dst[c4 + j] = f2bs(cwp[j]);
        #pragma unroll
        for (int j = 0; j < 4; ++j) dst[16 + c4 + j] = 0;
    }
    // Ps swizzle bases (bank-spread, from R6)
    const int rsw = (lq >> 2) & 3;
    const short* pa_rd = Ps + lq*40 + ((quad ^ rsw) << 3);
    short* pd_base = Ps + (w*16 + quad*4)*40 + (lq & 7);
    // K staging geometry: thread covers row kr, cols ksg..+32
    const int kr = tid >> 3, ksg = (tid & 7)*32;
    short* kdst = Ks + kr*264 + ksg;
    float alpha = af32 ? ((const float*)alphap)[0] : bs2f(((const short*)alphap)[0]);

    short8 qa[8];
    {
        const short* qrow = Qh + (size_t)(b*SS + q0 + w*16 + lq)*MID + quad*8;
        #pragma unroll
        for (int ks = 0; ks < 8; ++ks) qa[ks] = *(const short8*)(qrow + ks*32);
    }
    floatx4 acc[4][8];   // [qi][di]
    #pragma unroll
    for (int qi = 0; qi < 4; ++qi)
        #pragma unroll
        for (int di = 0; di < 8; ++di) acc[qi][di] = (floatx4){0.f,0.f,0.f,0.f};
    float l[4] = {0.f,0.f,0.f,0.f};

    const short* xb_base = xT + (size_t)(b*DDIM + d0 + w*128 + lq)*SS + quad*8;
    const short* ksrc0 = KKh + (size_t)(b*SS + kr)*MID + ksg;
    // prefetch K tile 0 into registers
    short8 kp0 = *(const short8*)(ksrc0);
    short8 kp1 = *(const short8*)(ksrc0 + 8);
    short8 kp2 = *(const short8*)(ksrc0 + 16);
    short8 kp3 = *(const short8*)(ksrc0 + 24);

    #pragma unroll 1
    for (int it = 0; it < ntiles; ++it) {
        const int t0 = it*32;
        // write prefetched K tile to LDS (prev QK readers crossed last barrier)
        *(short8*)(kdst)      = kp0;
        *(short8*)(kdst + 8)  = kp1;
        *(short8*)(kdst + 16) = kp2;
        *(short8*)(kdst + 24) = kp3;
        // issue next K prefetch (lands during this iter's QK+PV)
        if (it + 1 < ntiles) {
            const short* ks_n = ksrc0 + (size_t)(it + 1)*32*MID;
            kp0 = *(const short8*)(ks_n);
            kp1 = *(const short8*)(ks_n + 8);
            kp2 = *(const short8*)(ks_n + 16);
            kp3 = *(const short8*)(ks_n + 24);
        }
        // issue xf loads early: land during QK phase
        const short* xx = xb_base + it*32;
        short8 xf0 = *(const short8*)(xx);
        short8 xf1 = *(const short8*)(xx + (size_t)16*SS);
        short8 xf2 = *(const short8*)(xx + (size_t)32*SS);
        short8 xf3 = *(const short8*)(xx + (size_t)48*SS);
        short8 xf4 = *(const short8*)(xx + (size_t)64*SS);
        short8 xf5 = *(const short8*)(xx + (size_t)80*SS);
        short8 xf6 = *(const short8*)(xx + (size_t)96*SS);
        short8 xf7 = *(const short8*)(xx + (size_t)112*SS);
        __syncthreads();                          // Ks ready
        #pragma unroll
        for (int h = 0; h < 2; ++h) {
            floatx4 s = (floatx4){0.f,0.f,0.f,0.f};
            const short* kb = Ks + (h*16 + lq)*264 + quad*8;
            #pragma unroll
            for (int ks = 0; ks < 8; ++ks)
                s = MFMA16(qa[ks], *(const short8*)(kb + ks*32), s);
            int t = t0 + h*16 + lq;
            int qg = q0 + w*16 + quad*4;
            short* pd = pd_base + (((h*2 + (lq >> 3)) ^ quad) << 3);
            #pragma unroll
            for (int r = 0; r < 4; ++r) {
                float p = (t <= qg + r) ? __expf(s[r]) : 0.f;
                l[r] += p;
                pd[r*40] = f2bs(p);
            }
        }
        __syncthreads();                          // Ps ready
        {   // PV: pa from swizzled LDS, 8 d-tiles per wave
            short8 pa0 = *(const short8*)(pa_rd);
            short8 pa1 = *(const short8*)(pa_rd + 16*40);
            short8 pa2 = *(const short8*)(pa_rd + 32*40);
            short8 pa3 = *(const short8*)(pa_rd + 48*40);
            acc[0][0] = MFMA16(pa0, xf0, acc[0][0]);
            acc[1][0] = MFMA16(pa1, xf0, acc[1][0]);
            acc[2][0] = MFMA16(pa2, xf0, acc[2][0]);
            acc[3][0] = MFMA16(pa3, xf0, acc[3][0]);
            acc[0][1] = MFMA16(pa0, xf1, acc[0][1]);
            acc[1][1] = MFMA16(pa1, xf1, acc[1][1]);
            acc[2][1] = MFMA16(pa2, xf1, acc[2][1]);
            acc[3][1] = MFMA16(pa3, xf1, acc[3][1]);
            acc[0][2] = MFMA16(pa0, xf2, acc[0][2]);
            acc[1][2] = MFMA16(pa1, xf2, acc[1][2]);
            acc[2][2] = MFMA16(pa2, xf2, acc[2][2]);
            acc[3][2] = MFMA16(pa3, xf2, acc[3][2]);
            acc[0][3] = MFMA16(pa0, xf3, acc[0][3]);
            acc[1][3] = MFMA16(pa1, xf3, acc[1][3]);
            acc[2][3] = MFMA16(pa2, xf3, acc[2][3]);
            acc[3][3] = MFMA16(pa3, xf3, acc[3][3]);
            acc[0][4] = MFMA16(pa0, xf4, acc[0][4]);
            acc[1][4] = MFMA16(pa1, xf4, acc[1][4]);
            acc[2][4] = MFMA16(pa2, xf4, acc[2][4]);
            acc[3][4] = MFMA16(pa3, xf4, acc[3][4]);
            acc[0][5] = MFMA16(pa0, xf5, acc[0][5]);
            acc[1][5] = MFMA16(pa1, xf5, acc[1][5]);
            acc[2][5] = MFMA16(pa2, xf5, acc[2][5]);
            acc[3][5] = MFMA16(pa3, xf5, acc[3][5]);
            acc[0][6] = MFMA16(pa0, xf6, acc[0][6]);
            acc[1][6] = MFMA16(pa1, xf6, acc[1][6]);
            acc[2][6] = MFMA16(pa2, xf6, acc[2][6]);
            acc[3][6] = MFMA16(pa3, xf6, acc[3][6]);
            acc[0][7] = MFMA16(pa0, xf7, acc[0][7]);
            acc[1][7] = MFMA16(pa1, xf7, acc[1][7]);
            acc[2][7] = MFMA16(pa2, xf7, acc[2][7]);
            acc[3][7] = MFMA16(pa3, xf7, acc[3][7]);
        }
    }

    // softmax denominators: wave w computed l for rows w*16..+16
    #pragma unroll
    for (int r = 0; r < 4; ++r) {
        float v = l[r];
        v += __shfl_xor(v,1); v += __shfl_xor(v,2);
        v += __shfl_xor(v,4); v += __shfl_xor(v,8);
        if (lq == 0) lv[w*16 + quad*4 + r] = v;
    }
    __syncthreads();
    float linv[4][4];
    #pragma unroll
    for (int qi = 0; qi < 4; ++qi)
        #pragma unroll
        for (int r = 0; r < 4; ++r)
            linv[qi][r] = 1.f / lv[qi*16 + quad*4 + r];

    short8 ca[4];
    #pragma unroll
    for (int qi = 0; qi < 4; ++qi)
        ca[qi] = *(const short8*)(cwsb + (qi*16 + lq)*40 + quad*8);
    #pragma unroll
    for (int di = 0; di < 8; ++di) {
        const int dl = w*128 + di*16;             // local d of this tile
        const short8 cbf = *(const short8*)(cb1T + (dl + lq)*40 + quad*8);
        #pragma unroll
        for (int qi = 0; qi < 4; ++qi) {
            floatx4 tr = (floatx4){0.f,0.f,0.f,0.f};
            tr = MFMA16(ca[qi], cbf, tr);
            float* Ub = U + (size_t)(b*SS + q0 + qi*16 + quad*4)*DDIM + d0 + dl + lq;
            #pragma unroll
            for (int r = 0; r < 4; ++r) {
                float u = acc[qi][di][r]*linv[qi][r] + alpha*tr[r];
                float e2 = __expf(1.5957691216f*(u + 0.044715f*u*u*u));
                float th = 1.f - 2.f/(e2 + 1.f);
                Ub[(size_t)r*DDIM] = 0.5f*u*(1.f + th);
            }
        }
    }
}

// --------- final MFMA GEMM v2, in-place on d_out: out = U @ W^T + bias -------
__global__ __launch_bounds__(256,2) void k_gemm3(float* __restrict__ out,
        const float* __restrict__ ws) {
    __shared__ __align__(16) short Al[32*132];   // 8.4 KB (pad 4 shorts/row)
    const int tid = threadIdx.x;
    const int w = tid >> 6, lane = tid & 63;
    const int col = lane & 31, kh = lane >> 5;   // MFMA32: row/col = lane&31, k-half = lane>>5
    const int m0 = blockIdx.x*32;
    const int n0 = w*256;
    const short* Wb = (const short*)(ws + WS_WB);
    const float* biasf = ws + WS_BIAS;

    floatx16 acc[8];
    #pragma unroll
    for (int nt = 0; nt < 8; ++nt)
        #pragma unroll
        for (int r = 0; r < 16; ++r) acc[nt][r] = 0.f;

    const int srow = tid >> 3, sk = (tid & 7)*16;
    const float* Usrc = out + (size_t)(m0 + srow)*DDIM + sk;
    short* Adst = Al + srow*132 + sk;

    #pragma unroll 1
    for (int kc = 0; kc < DDIM; kc += 128) {
        __syncthreads();
        {   // stage A chunk [32][128] f32 -> bf16
            const float* s = Usrc + kc;
            float4 a = *(const float4*)s,     b4 = *(const float4*)(s + 4);
            float4 c = *(const float4*)(s+8), d  = *(const float4*)(s + 12);
            short8 v0, v1;
            v0[0]=f2bs(a.x);  v0[1]=f2bs(a.y);  v0[2]=f2bs(a.z);  v0[3]=f2bs(a.w);
            v0[4]=f2bs(b4.x); v0[5]=f2bs(b4.y); v0[6]=f2bs(b4.z); v0[7]=f2bs(b4.w);
            v1[0]=f2bs(c.x);  v1[1]=f2bs(c.y);  v1[2]=f2bs(c.z);  v1[3]=f2bs(c.w);
            v1[4]=f2bs(d.x);  v1[5]=f2bs(d.y);  v1[6]=f2bs(d.z);  v1[7]=f2bs(d.w);
            *(short8*)(Adst)     = v0;
            *(short8*)(Adst + 8) = v1;
        }
        __syncthreads();
        const short* wbp0 = Wb + (size_t)(n0 + col)*DDIM + kc + kh*8;
        #pragma unroll
        for (int ks = 0; ks < 8; ++ks) {
            short8 af = *(const short8*)(Al + col*132 + ks*16 + kh*8);
            const short* wbp = wbp0 + ks*16;
            #pragma unroll
            for (int nt = 0; nt < 8; ++nt)
                acc[nt] = MFMA32(af, *(const short8*)(wbp + (size_t)nt*32*DDIM), acc[nt]);
        }
    }
    // all U reads finished at the last staging barrier -> in-place write safe
    #pragma unroll
    for (int nt = 0; nt < 8; ++nt) {
        int c = n0 + nt*32 + col;
        float bb = biasf[c];
        #pragma unroll
        for (int r = 0; r < 16; ++r) {
            int row = (r & 3) + 8*(r >> 2) + 4*kh;
            out[(size_t)(m0 + row)*DDIM + c] = acc[nt][r] + bb;
        }
    }
}

extern "C" void kernel_launch(void* const* d_in, const int* in_sizes, int n_in,
                              void* d_out, int out_size, void* d_ws, size_t ws_size,
                              hipStream_t stream) {
    (void)out_size; (void)ws_size;
    const void* x    = d_in[0];
    const int*  nidx = (const int*)d_in[1];
    const void* nw   = d_in[2];
    const void* rmat = d_in[3];
    const void* rb   = d_in[4];
    const void* cb   = d_in[5];
    const void* w    = d_in[6];
    const void* bias = d_in[7];
    const void* alpha= d_in[8];
    float* ws = (float*)d_ws;
    float* out = (float*)d_out;

    DetectArgs da;
    for (int i = 0; i < 9; ++i) { da.p[i] = d_in[i]; da.n[i] = (i < n_in) ? in_sizes[i] : 1; }

    k_detect<<<10, 256, 0, stream>>>(da, (int*)ws);
    k_rbsum<<<128, 256, 0, stream>>>(rb, ws);
    k_cb2  <<<1024, 256, 0, stream>>>(cb, ws);
    k_cb1  <<<256, 256, 0, stream>>>(cb, ws);
    k_wcvt <<<513, 256, 0, stream>>>(w, bias, ws);
    k_xt   <<<dim3(SS/64, DDIM/64, BB), 256, 0, stream>>>(x, ws);
    k_route<<<TOK/4, 256, 0, stream>>>(nidx, nw, rmat, ws);
    k_att  <<<512, 256, 0, stream>>>(ws, out, alpha);
    k_gemm3<<<TOK/32, 256, 0, stream>>>(out, ws);
}